// Round 3
// baseline (563.735 us; speedup 1.0000x reference)
//
#include <hip/hip_runtime.h>
#include <stdint.h>
#include <stddef.h>

#define TOK    16384     // B*S
#define DDIM   1024
#define NEXP   8
#define BMT    128       // expert gemm row tile (padding quantum)
#define RB_MAX 136       // ceil((TOK + NEXP*BMT)/BMT) upper bound
#define MARGIN 1e-3f     // split-logit ambiguity margin (~22 sigma of split err)
#define AMBIG_CAP 1024
#define NINF  (-3.0e38f)

typedef __bf16 bf16x8 __attribute__((ext_vector_type(8)));
typedef float  f32x4  __attribute__((ext_vector_type(4)));

__device__ __forceinline__ unsigned short f2bf(float f) {
    unsigned int u = __float_as_uint(f);
    u += 0x7fff + ((u >> 16) & 1);          // round-to-nearest-even
    return (unsigned short)(u >> 16);
}
__device__ __forceinline__ float bf2f(unsigned short h) {
    return __uint_as_float((unsigned int)h << 16);
}

__device__ __forceinline__ void gload_lds16(const void* g, void* l) {
    __builtin_amdgcn_global_load_lds(
        (const __attribute__((address_space(1))) unsigned int*)g,
        (__attribute__((address_space(3))) unsigned int*)l, 16, 0, 0);
}

// ---------------------------------------------------------------------------
// Weight prep, fused: z<8 -> We[e][k][n] fp32 -> WeT[e][n][k] bf16;
//                     z==8 -> Wg[k][n] -> WgT hi/lo bf16 split.
// ---------------------------------------------------------------------------
__global__ __launch_bounds__(256) void prep_weights(
    const float* __restrict__ We, const float* __restrict__ Wg,
    unsigned short* __restrict__ WeT,
    unsigned short* __restrict__ Wh, unsigned short* __restrict__ Wl)
{
    __shared__ float tile[32][33];
    const int z  = blockIdx.z;
    const int k0 = blockIdx.x * 32;
    const int n0 = blockIdx.y * 32;
    const int tx = threadIdx.x;   // 0..31
    const int ty = threadIdx.y;   // 0..7
    const float* src = (z < NEXP) ? We + (size_t)z * DDIM * DDIM : Wg;
#pragma unroll
    for (int r = 0; r < 4; r++)
        tile[ty + r * 8][tx] = src[(size_t)(k0 + ty + r * 8) * DDIM + n0 + tx];
    __syncthreads();
    if (z < NEXP) {
        unsigned short* dst = WeT + (size_t)z * DDIM * DDIM;
#pragma unroll
        for (int r = 0; r < 4; r++)
            dst[(size_t)(n0 + ty + r * 8) * DDIM + k0 + tx] = f2bf(tile[tx][ty + r * 8]);
    } else {
#pragma unroll
        for (int r = 0; r < 4; r++) {
            float v = tile[tx][ty + r * 8];
            unsigned short h = f2bf(v);
            size_t o = (size_t)(n0 + ty + r * 8) * DDIM + k0 + tx;
            Wh[o] = h; Wl[o] = f2bf(v - bf2f(h));
        }
    }
}

// ---------------------------------------------------------------------------
// x fp32 -> xh (bf16 hi), xl (bf16 residual), same [tok][k] layout
// ---------------------------------------------------------------------------
__global__ __launch_bounds__(256) void xsplit(
    const float* __restrict__ x, unsigned short* __restrict__ xh,
    unsigned short* __restrict__ xl)
{
    const size_t i = ((size_t)blockIdx.x * 256 + threadIdx.x) * 4;
    float4 v = *(const float4*)&x[i];
    ushort4 h, l;
    h.x = f2bf(v.x); l.x = f2bf(v.x - bf2f(h.x));
    h.y = f2bf(v.y); l.y = f2bf(v.y - bf2f(h.y));
    h.z = f2bf(v.z); l.z = f2bf(v.z - bf2f(h.z));
    h.w = f2bf(v.w); l.w = f2bf(v.w - bf2f(h.w));
    *(ushort4*)&xh[i] = h;
    *(ushort4*)&xl[i] = l;
}

// ---------------------------------------------------------------------------
// Gating GEMM on matrix cores, double-bf16 split (3 MFMA products), with the
// row-stats fused into the epilogue: per 128x128 tile, emit per-row
// (top1, top2, sumexp, argcol) partials [nb][row]. No logits materialized.
// Pure global_load_lds staging (A from precomputed xh/xl).
// ---------------------------------------------------------------------------
__global__ __launch_bounds__(256) void gating_mfma(
    const unsigned short* __restrict__ xh, const unsigned short* __restrict__ xl,
    const unsigned short* __restrict__ WgTh, const unsigned short* __restrict__ WgTl,
    const float* __restrict__ bg, float4* __restrict__ partials)
{
    __shared__ unsigned short Ah[128 * 32], Al[128 * 32];
    __shared__ unsigned short Bh[128 * 32], Bl[128 * 32];
    __shared__ float4 stat[128][2];
    const int rb = blockIdx.x;
    const int nb = blockIdx.y;
    const int tid  = threadIdx.x;
    const int lane = tid & 63;
    const int wave = tid >> 6;
    const int q    = lane >> 4;
    const int m16  = lane & 15;
    const int wrow = (wave & 1) * 64;
    const int wcol = (wave >> 1) * 64;
    const int half = wave >> 1;
    const int xq   = (q ^ (m16 & 3)) * 8;

    const unsigned short* Ahg = xh + (size_t)rb * 128 * DDIM;
    const unsigned short* Alg = xl + (size_t)rb * 128 * DDIM;
    const unsigned short* Bhg = WgTh + (size_t)nb * 128 * DDIM;
    const unsigned short* Blg = WgTl + (size_t)nb * 128 * DDIM;

    f32x4 acc[4][4];
#pragma unroll
    for (int i = 0; i < 4; i++)
#pragma unroll
        for (int j = 0; j < 4; j++) acc[i][j] = (f32x4){0.f, 0.f, 0.f, 0.f};

    for (int k0 = 0; k0 < DDIM; k0 += 32) {
#pragma unroll
        for (int i = 0; i < 2; i++) {
            const int idx = tid + i * 256;
            const int r = idx >> 2;
            const int kk = ((idx & 3) ^ (r & 3)) * 8;
            const size_t go = (size_t)r * DDIM + k0 + kk;
            gload_lds16(Ahg + go, &Ah[idx * 8]);
            gload_lds16(Alg + go, &Al[idx * 8]);
            gload_lds16(Bhg + go, &Bh[idx * 8]);
            gload_lds16(Blg + go, &Bl[idx * 8]);
        }
        __syncthreads();
        bf16x8 ah[4], al[4], bhf[4], blf[4];
#pragma unroll
        for (int i = 0; i < 4; i++) {
            ah[i] = *(const bf16x8*)&Ah[(wrow + i * 16 + m16) * 32 + xq];
            al[i] = *(const bf16x8*)&Al[(wrow + i * 16 + m16) * 32 + xq];
        }
#pragma unroll
        for (int j = 0; j < 4; j++) {
            bhf[j] = *(const bf16x8*)&Bh[(wcol + j * 16 + m16) * 32 + xq];
            blf[j] = *(const bf16x8*)&Bl[(wcol + j * 16 + m16) * 32 + xq];
        }
#pragma unroll
        for (int i = 0; i < 4; i++)
#pragma unroll
            for (int j = 0; j < 4; j++) {
                acc[i][j] = __builtin_amdgcn_mfma_f32_16x16x32_bf16(ah[i], bhf[j], acc[i][j], 0, 0, 0);
                acc[i][j] = __builtin_amdgcn_mfma_f32_16x16x32_bf16(ah[i], blf[j], acc[i][j], 0, 0, 0);
                acc[i][j] = __builtin_amdgcn_mfma_f32_16x16x32_bf16(al[i], bhf[j], acc[i][j], 0, 0, 0);
            }
        __syncthreads();
    }

    // ---- fused row stats over this 128x128 tile ----
    float bgv[4];
#pragma unroll
    for (int j = 0; j < 4; j++) bgv[j] = bg[nb * 128 + wcol + j * 16 + m16];

#pragma unroll
    for (int i = 0; i < 4; i++) {
#pragma unroll
        for (int r = 0; r < 4; r++) {
            const int rloc = wrow + i * 16 + q * 4 + r;
            float v[4];
#pragma unroll
            for (int j = 0; j < 4; j++) v[j] = acc[i][j][r] + bgv[j];
            // lane-local top2 over the 4 cols (ascending col order -> strict >)
            float t1 = v[0], t2 = NINF;
            int c1 = nb * 128 + wcol + m16;
#pragma unroll
            for (int j = 1; j < 4; j++) {
                const int cj = nb * 128 + wcol + j * 16 + m16;
                if (v[j] > t1) { t2 = t1; t1 = v[j]; c1 = cj; }
                else t2 = fmaxf(t2, v[j]);
            }
            // xor-reduce across the 16 lanes sharing q (masks stay in-group)
#pragma unroll
            for (int mask = 1; mask <= 8; mask <<= 1) {
                float o1 = __shfl_xor(t1, mask, 64);
                int   oc = __shfl_xor(c1, mask, 64);
                float o2 = __shfl_xor(t2, mask, 64);
                if (o1 > t1 || (o1 == t1 && oc < c1)) {
                    t2 = fmaxf(t1, o2); t1 = o1; c1 = oc;
                } else {
                    t2 = fmaxf(t2, o1);
                }
            }
            // sumexp relative to half-tile max
            float s = expf(v[0] - t1) + expf(v[1] - t1) +
                      expf(v[2] - t1) + expf(v[3] - t1);
#pragma unroll
            for (int mask = 1; mask <= 8; mask <<= 1)
                s += __shfl_xor(s, mask, 64);
            if (m16 == 0) {
                float4 st; st.x = t1; st.y = t2; st.z = s; st.w = __int_as_float(c1);
                stat[rloc][half] = st;
            }
        }
    }
    __syncthreads();
    if (tid < 128) {
        float4 h0 = stat[tid][0], h1 = stat[tid][1];   // h0 = lower cols
        float T1 = h0.x, T2 = h0.y, S;
        int C = __float_as_int(h0.w);
        if (h1.x > T1) {
            T2 = fmaxf(T1, h1.y);
            S = h0.z * expf(T1 - h1.x) + h1.z;
            T1 = h1.x; C = __float_as_int(h1.w);
        } else {
            T2 = fmaxf(T2, h1.x);
            S = h0.z + h1.z * expf(h1.x - T1);
        }
        float4 o; o.x = T1; o.y = T2; o.z = S; o.w = __int_as_float(C);
        partials[(size_t)nb * TOK + rb * 128 + tid] = o;
    }
}

// ---------------------------------------------------------------------------
// Combine 8 tile-partials per row -> p, e; flag ambiguous rows (gap < MARGIN)
// ---------------------------------------------------------------------------
__global__ __launch_bounds__(256) void row_combine(
    const float4* __restrict__ partials, float* __restrict__ pout,
    int* __restrict__ eout, int* __restrict__ ambig, int* __restrict__ n_ambig)
{
    const int row = blockIdx.x * 256 + threadIdx.x;
    float4 t = partials[row];                 // nb = 0
    float T1 = t.x, T2 = t.y, S = t.z;
    int C = __float_as_int(t.w);
#pragma unroll
    for (int nb = 1; nb < NEXP; nb++) {
        float4 u = partials[(size_t)nb * TOK + row];
        if (u.x > T1) {
            T2 = fmaxf(T1, u.y);
            S = S * expf(T1 - u.x) + u.z;
            T1 = u.x; C = __float_as_int(u.w);
        } else {
            T2 = fmaxf(T2, u.x);
            S += u.z * expf(u.x - T1);
        }
    }
    pout[row] = 1.0f / S;
    eout[row] = C & (NEXP - 1);
    if (T1 - T2 < MARGIN) {
        int k = atomicAdd(n_ambig, 1);
        if (k < AMBIG_CAP) ambig[k] = row;
    }
}

// ---------------------------------------------------------------------------
// Fix-up: ambiguous rows get the WHOLE row recomputed in fp64 from the
// original fp32 x, Wg (coalesced: at fixed k, threads read contiguous cols).
// Commits exact argmax (numpy first-occurrence) and exact p.
// ---------------------------------------------------------------------------
__global__ __launch_bounds__(256) void fixup(
    const float* __restrict__ x, const float* __restrict__ Wg,
    const float* __restrict__ bg, const int* __restrict__ ambig,
    const int* __restrict__ n_ambig, int* __restrict__ eout,
    float* __restrict__ pout)
{
    int n = *n_ambig; if (n > AMBIG_CAP) n = AMBIG_CAP;
    if ((int)blockIdx.x >= n) return;
    const int row = ambig[blockIdx.x];
    const int tid = threadIdx.x;
    __shared__ float xs[DDIM];
    for (int k = tid; k < DDIM; k += 256) xs[k] = x[(size_t)row * DDIM + k];
    __syncthreads();
    double a0 = 0, a1 = 0, a2 = 0, a3 = 0;
    for (int k = 0; k < DDIM; k++) {
        const double xv = (double)xs[k];
        const float* wr = Wg + (size_t)k * DDIM;
        a0 += xv * (double)wr[tid];
        a1 += xv * (double)wr[tid + 256];
        a2 += xv * (double)wr[tid + 512];
        a3 += xv * (double)wr[tid + 768];
    }
    a0 += (double)bg[tid];       a1 += (double)bg[tid + 256];
    a2 += (double)bg[tid + 512]; a3 += (double)bg[tid + 768];
    double m = a0; int mc = tid;
    if (a1 > m) { m = a1; mc = tid + 256; }
    if (a2 > m) { m = a2; mc = tid + 512; }
    if (a3 > m) { m = a3; mc = tid + 768; }
    __shared__ double sv[256];
    __shared__ int    si[256];
    sv[tid] = m; si[tid] = mc;
    __syncthreads();
    for (int off = 128; off > 0; off >>= 1) {
        if (tid < off) {
            double ov = sv[tid + off]; int oi = si[tid + off];
            if (ov > sv[tid] || (ov == sv[tid] && oi < si[tid])) {
                sv[tid] = ov; si[tid] = oi;
            }
        }
        __syncthreads();
    }
    const double M = sv[0];
    const int best = si[0];
    __syncthreads();
    double s = exp(a0 - M) + exp(a1 - M) + exp(a2 - M) + exp(a3 - M);
    sv[tid] = s;
    __syncthreads();
    for (int off = 128; off > 0; off >>= 1) {
        if (tid < off) sv[tid] += sv[tid + off];
        __syncthreads();
    }
    if (tid == 0) {
        eout[row] = best & (NEXP - 1);
        pout[row] = (float)(1.0 / sv[0]);
    }
}

// ---------------------------------------------------------------------------
// One block: expert histogram + padded starts + block->expert map + cursor=0
// ---------------------------------------------------------------------------
__global__ __launch_bounds__(256) void histo_offsets(
    const int* __restrict__ eout, int* __restrict__ start,
    int* __restrict__ blk_expert, int* __restrict__ cursor)
{
    __shared__ int h[NEXP];
    const int tid = threadIdx.x;
    if (tid < NEXP) h[tid] = 0;
    __syncthreads();
    for (int t = tid; t < TOK; t += 256) atomicAdd(&h[eout[t]], 1);
    __syncthreads();
    if (tid == 0) {
        int st[NEXP + 1];
        int total = 0;
        for (int e = 0; e < NEXP; e++) {
            st[e] = total;
            total += ((h[e] + BMT - 1) / BMT) * BMT;
            cursor[e] = 0;
        }
        st[NEXP] = total;
        for (int e = 0; e <= NEXP; e++) start[e] = st[e];
        for (int rb = 0; rb < RB_MAX; rb++) {
            int s = rb * BMT;
            int ex = -1;
            for (int e = 0; e < NEXP; e++)
                if (s >= st[e] && s < st[e + 1]) ex = e;
            blk_expert[rb] = ex;
        }
    }
}

// ---------------------------------------------------------------------------
// token -> slot (atomic cursor per expert)
// ---------------------------------------------------------------------------
__global__ __launch_bounds__(256) void assign_slots(
    const int* __restrict__ eout, const int* __restrict__ start,
    int* __restrict__ cursor, int* __restrict__ row_of_slot)
{
    int t = blockIdx.x * 256 + threadIdx.x;
    if (t >= TOK) return;
    int e = eout[t];
    int slot = start[e] + atomicAdd(&cursor[e], 1);
    row_of_slot[slot] = t;
}

// ---------------------------------------------------------------------------
// Expert GEMM: A gathered from bf16 xh via row_of_slot with per-lane-address
// global_load_lds (LDS dst stays wave-uniform+lane*16); B = WeT gload_lds.
// bf16 MFMA 16x16x32, 128x128 tile, BK=32. Epilogue relu(acc+be)*p scatter.
// ---------------------------------------------------------------------------
__global__ __launch_bounds__(256) void expert_gemm(
    const unsigned short* __restrict__ xh, const unsigned short* __restrict__ WeT,
    const float* __restrict__ be, const float* __restrict__ p,
    const int* __restrict__ row_of_slot, const int* __restrict__ blk_expert,
    float* __restrict__ out)
{
    __shared__ unsigned short Asm[128 * 32];
    __shared__ unsigned short Bsm[128 * 32];
    __shared__ int rs[128];
    const int rb = blockIdx.x;
    const int nb = blockIdx.y;
    const int e = blk_expert[rb];
    if (e < 0) return;

    const int tid  = threadIdx.x;
    const int lane = tid & 63;
    const int wave = tid >> 6;
    const int q    = lane >> 4;
    const int m16  = lane & 15;
    const int wrow = (wave & 1) * 64;
    const int wcol = (wave >> 1) * 64;
    const int xq   = (q ^ (m16 & 3)) * 8;

    if (tid < 128) rs[tid] = row_of_slot[rb * 128 + tid];
    __syncthreads();

    // hoist gather rows for the two staging issues
    int srow[2], skk[2];
#pragma unroll
    for (int i = 0; i < 2; i++) {
        const int idx = tid + i * 256;
        const int r = idx >> 2;
        skk[i] = ((idx & 3) ^ (r & 3)) * 8;
        const int t = rs[r];
        srow[i] = t < 0 ? 0 : t;      // pad rows: stage row 0, discard in epilogue
    }

    const unsigned short* Bglob = WeT + (size_t)e * DDIM * DDIM + (size_t)nb * 128 * DDIM;

    f32x4 acc[4][4];
#pragma unroll
    for (int i = 0; i < 4; i++)
#pragma unroll
        for (int j = 0; j < 4; j++) acc[i][j] = (f32x4){0.f, 0.f, 0.f, 0.f};

    for (int k0 = 0; k0 < DDIM; k0 += 32) {
#pragma unroll
        for (int i = 0; i < 2; i++) {
            const int idx = tid + i * 256;
            const int r = idx >> 2;
            gload_lds16(Bglob + (size_t)r * DDIM + k0 + skk[i], &Bsm[idx * 8]);
            gload_lds16(xh + (size_t)srow[i] * DDIM + k0 + skk[i], &Asm[idx * 8]);
        }
        __syncthreads();
        bf16x8 af[4], bfr[4];
#pragma unroll
        for (int i = 0; i < 4; i++)
            af[i] = *(const bf16x8*)&Asm[(wrow + i * 16 + m16) * 32 + xq];
#pragma unroll
        for (int j = 0; j < 4; j++)
            bfr[j] = *(const bf16x8*)&Bsm[(wcol + j * 16 + m16) * 32 + xq];
#pragma unroll
        for (int i = 0; i < 4; i++)
#pragma unroll
            for (int j = 0; j < 4; j++)
                acc[i][j] = __builtin_amdgcn_mfma_f32_16x16x32_bf16(
                    af[i], bfr[j], acc[i][j], 0, 0, 0);
        __syncthreads();
    }

    float bev[4];
#pragma unroll
    for (int j = 0; j < 4; j++) bev[j] = be[e * DDIM + nb * 128 + wcol + j * 16 + m16];
#pragma unroll
    for (int i = 0; i < 4; i++)
#pragma unroll
        for (int r = 0; r < 4; r++) {
            const int t = rs[wrow + i * 16 + q * 4 + r];
            if (t < 0) continue;
            const float pv = p[t];
#pragma unroll
            for (int j = 0; j < 4; j++) {
                const int n = nb * 128 + wcol + j * 16 + m16;
                float v = acc[i][j][r] + bev[j];
                v = v > 0.f ? v : 0.f;
                out[(size_t)t * DDIM + n] = v * pv;
            }
        }
}

// ---------------------------------------------------------------------------
extern "C" void kernel_launch(void* const* d_in, const int* in_sizes, int n_in,
                              void* d_out, int out_size, void* d_ws, size_t ws_size,
                              hipStream_t stream)
{
    const float* x  = (const float*)d_in[0];
    const float* Wg = (const float*)d_in[1];
    const float* bg = (const float*)d_in[2];
    const float* We = (const float*)d_in[3];
    const float* be = (const float*)d_in[4];
    float* out = (float*)d_out;

    char* ws = (char*)d_ws;
    unsigned short* xh = (unsigned short*)ws;   ws += (size_t)TOK * DDIM * 2;
    unsigned short* xl = (unsigned short*)ws;   ws += (size_t)TOK * DDIM * 2;
    unsigned short* WeT = (unsigned short*)ws;  ws += (size_t)NEXP * DDIM * DDIM * 2;
    unsigned short* WgTh = (unsigned short*)ws; ws += (size_t)DDIM * DDIM * 2;
    unsigned short* WgTl = (unsigned short*)ws; ws += (size_t)DDIM * DDIM * 2;
    float4* partials = (float4*)ws;             ws += (size_t)NEXP * TOK * 16;
    float* p = (float*)ws;                      ws += (size_t)TOK * 4;
    int* e_arr = (int*)ws;                      ws += (size_t)TOK * 4;
    int* row_of_slot = (int*)ws;                ws += (size_t)RB_MAX * BMT * 4;
    int* cursor = (int*)ws;                     ws += NEXP * 4;
    int* start = (int*)ws;                      ws += (NEXP + 1) * 4;
    int* blk_expert = (int*)ws;                 ws += RB_MAX * 4;
    int* ambig = (int*)ws;                      ws += AMBIG_CAP * 4;
    int* n_ambig = (int*)ws;                    ws += 4;

    hipMemsetAsync(n_ambig, 0, 4, stream);
    hipMemsetAsync(row_of_slot, 0xFF, (size_t)RB_MAX * BMT * 4, stream);

    prep_weights<<<dim3(32, 32, NEXP + 1), dim3(32, 8), 0, stream>>>(We, Wg, WeT, WgTh, WgTl);
    xsplit<<<TOK * DDIM / 1024, 256, 0, stream>>>(x, xh, xl);
    gating_mfma<<<dim3(TOK / 128, DDIM / 128), 256, 0, stream>>>(
        xh, xl, WgTh, WgTl, bg, partials);
    row_combine<<<TOK / 256, 256, 0, stream>>>(partials, p, e_arr, ambig, n_ambig);
    fixup<<<AMBIG_CAP, 256, 0, stream>>>(x, Wg, bg, ambig, n_ambig, e_arr, p);
    histo_offsets<<<1, 256, 0, stream>>>(e_arr, start, blk_expert, cursor);
    assign_slots<<<TOK / 256, 256, 0, stream>>>(e_arr, start, cursor, row_of_slot);
    expert_gemm<<<dim3(RB_MAX, DDIM / 128), 256, 0, stream>>>(
        xh, WeT, be, p, row_of_slot, blk_expert, out);
}

// Round 4
// 497.154 us; speedup vs baseline: 1.1339x; 1.1339x over previous
//
#include <hip/hip_runtime.h>
#include <stdint.h>
#include <stddef.h>

#define TOK    16384     // B*S
#define DDIM   1024
#define NEXP   8
#define CAPB   20        // 128-row blocks per expert (capacity 2560 >= 2048+12sigma)
#define CAP    (CAPB * 128)
#define NRB    (CAPB * NEXP)   // 160 row-blocks total
#define MARGIN 2e-4f     // split-logit ambiguity margin (~40 sigma of split err)
#define AMBIG_CAP 1024
#define NINF  (-3.0e38f)

typedef __bf16 bf16x8 __attribute__((ext_vector_type(8)));
typedef float  f32x4  __attribute__((ext_vector_type(4)));

__device__ __forceinline__ unsigned short f2bf(float f) {
    unsigned int u = __float_as_uint(f);
    u += 0x7fff + ((u >> 16) & 1);          // round-to-nearest-even
    return (unsigned short)(u >> 16);
}
__device__ __forceinline__ float bf2f(unsigned short h) {
    return __uint_as_float((unsigned int)h << 16);
}

__device__ __forceinline__ void gload_lds16(const void* g, void* l) {
    __builtin_amdgcn_global_load_lds(
        (const __attribute__((address_space(1))) unsigned int*)g,
        (__attribute__((address_space(3))) unsigned int*)l, 16, 0, 0);
}

// ---------------------------------------------------------------------------
// Weight prep: z<8 -> We[e][k][n] -> WeT[e][n][k] bf16; z==8 -> Wg -> hi/lo
// split transposed. ushort4 stores (64B per 8 lanes vs 2B scalar before).
// ---------------------------------------------------------------------------
__global__ __launch_bounds__(256) void prep_weights(
    const float* __restrict__ We, const float* __restrict__ Wg,
    unsigned short* __restrict__ WeT,
    unsigned short* __restrict__ Wh, unsigned short* __restrict__ Wl)
{
    __shared__ float tile[32][33];
    const int z  = blockIdx.z;
    const int k0 = blockIdx.x * 32;
    const int n0 = blockIdx.y * 32;
    const int tx = threadIdx.x;   // 0..31
    const int ty = threadIdx.y;   // 0..7
    const float* src = (z < NEXP) ? We + (size_t)z * DDIM * DDIM : Wg;
#pragma unroll
    for (int r = 0; r < 4; r++)
        tile[ty + r * 8][tx] = src[(size_t)(k0 + ty + r * 8) * DDIM + n0 + tx];
    __syncthreads();
    const int i  = ty * 32 + tx;   // 0..255
    const int nl = i >> 3;         // local n 0..31
    const int kq = (i & 7) * 4;    // local k quad 0,4..28
    const size_t o = (size_t)(n0 + nl) * DDIM + k0 + kq;
    if (z < NEXP) {
        unsigned short* dst = WeT + (size_t)z * DDIM * DDIM;
        ushort4 hv;
        hv.x = f2bf(tile[kq + 0][nl]); hv.y = f2bf(tile[kq + 1][nl]);
        hv.z = f2bf(tile[kq + 2][nl]); hv.w = f2bf(tile[kq + 3][nl]);
        *(ushort4*)&dst[o] = hv;
    } else {
        ushort4 hv, lv;
        float v0 = tile[kq + 0][nl], v1 = tile[kq + 1][nl];
        float v2 = tile[kq + 2][nl], v3 = tile[kq + 3][nl];
        hv.x = f2bf(v0); lv.x = f2bf(v0 - bf2f(hv.x));
        hv.y = f2bf(v1); lv.y = f2bf(v1 - bf2f(hv.y));
        hv.z = f2bf(v2); lv.z = f2bf(v2 - bf2f(hv.z));
        hv.w = f2bf(v3); lv.w = f2bf(v3 - bf2f(hv.w));
        *(ushort4*)&Wh[o] = hv;
        *(ushort4*)&Wl[o] = lv;
    }
}

// ---------------------------------------------------------------------------
// x fp32 -> xh (bf16 hi), xl (bf16 residual)
// ---------------------------------------------------------------------------
__global__ __launch_bounds__(256) void xsplit(
    const float* __restrict__ x, unsigned short* __restrict__ xh,
    unsigned short* __restrict__ xl)
{
    const size_t i = ((size_t)blockIdx.x * 256 + threadIdx.x) * 4;
    float4 v = *(const float4*)&x[i];
    ushort4 h, l;
    h.x = f2bf(v.x); l.x = f2bf(v.x - bf2f(h.x));
    h.y = f2bf(v.y); l.y = f2bf(v.y - bf2f(h.y));
    h.z = f2bf(v.z); l.z = f2bf(v.z - bf2f(h.z));
    h.w = f2bf(v.w); l.w = f2bf(v.w - bf2f(h.w));
    *(ushort4*)&xh[i] = h;
    *(ushort4*)&xl[i] = l;
}

// ---------------------------------------------------------------------------
// Gating GEMM on matrix cores (3-term bf16 split), row-stats fused:
// per 128x128 tile emit per-row (top1, top2, sumexp, argcol) partials.
// ---------------------------------------------------------------------------
__global__ __launch_bounds__(256) void gating_mfma(
    const unsigned short* __restrict__ xh, const unsigned short* __restrict__ xl,
    const unsigned short* __restrict__ WgTh, const unsigned short* __restrict__ WgTl,
    const float* __restrict__ bg, float4* __restrict__ partials)
{
    __shared__ unsigned short Ah[128 * 32], Al[128 * 32];
    __shared__ unsigned short Bh[128 * 32], Bl[128 * 32];
    __shared__ float4 stat[128][2];
    const int rb = blockIdx.x;
    const int nb = blockIdx.y;
    const int tid  = threadIdx.x;
    const int lane = tid & 63;
    const int wave = tid >> 6;
    const int q    = lane >> 4;
    const int m16  = lane & 15;
    const int wrow = (wave & 1) * 64;
    const int wcol = (wave >> 1) * 64;
    const int half = wave >> 1;
    const int xq   = (q ^ (m16 & 3)) * 8;

    const unsigned short* Ahg = xh + (size_t)rb * 128 * DDIM;
    const unsigned short* Alg = xl + (size_t)rb * 128 * DDIM;
    const unsigned short* Bhg = WgTh + (size_t)nb * 128 * DDIM;
    const unsigned short* Blg = WgTl + (size_t)nb * 128 * DDIM;

    f32x4 acc[4][4];
#pragma unroll
    for (int i = 0; i < 4; i++)
#pragma unroll
        for (int j = 0; j < 4; j++) acc[i][j] = (f32x4){0.f, 0.f, 0.f, 0.f};

    for (int k0 = 0; k0 < DDIM; k0 += 32) {
#pragma unroll
        for (int i = 0; i < 2; i++) {
            const int idx = tid + i * 256;
            const int r = idx >> 2;
            const int kk = ((idx & 3) ^ (r & 3)) * 8;
            const size_t go = (size_t)r * DDIM + k0 + kk;
            gload_lds16(Ahg + go, &Ah[idx * 8]);
            gload_lds16(Alg + go, &Al[idx * 8]);
            gload_lds16(Bhg + go, &Bh[idx * 8]);
            gload_lds16(Blg + go, &Bl[idx * 8]);
        }
        __syncthreads();
        bf16x8 ah[4], al[4], bhf[4], blf[4];
#pragma unroll
        for (int i = 0; i < 4; i++) {
            ah[i] = *(const bf16x8*)&Ah[(wrow + i * 16 + m16) * 32 + xq];
            al[i] = *(const bf16x8*)&Al[(wrow + i * 16 + m16) * 32 + xq];
        }
#pragma unroll
        for (int j = 0; j < 4; j++) {
            bhf[j] = *(const bf16x8*)&Bh[(wcol + j * 16 + m16) * 32 + xq];
            blf[j] = *(const bf16x8*)&Bl[(wcol + j * 16 + m16) * 32 + xq];
        }
#pragma unroll
        for (int i = 0; i < 4; i++)
#pragma unroll
            for (int j = 0; j < 4; j++) {
                acc[i][j] = __builtin_amdgcn_mfma_f32_16x16x32_bf16(ah[i], bhf[j], acc[i][j], 0, 0, 0);
                acc[i][j] = __builtin_amdgcn_mfma_f32_16x16x32_bf16(ah[i], blf[j], acc[i][j], 0, 0, 0);
                acc[i][j] = __builtin_amdgcn_mfma_f32_16x16x32_bf16(al[i], bhf[j], acc[i][j], 0, 0, 0);
            }
        __syncthreads();
    }

    float bgv[4];
#pragma unroll
    for (int j = 0; j < 4; j++) bgv[j] = bg[nb * 128 + wcol + j * 16 + m16];

#pragma unroll
    for (int i = 0; i < 4; i++) {
#pragma unroll
        for (int r = 0; r < 4; r++) {
            const int rloc = wrow + i * 16 + q * 4 + r;
            float v[4];
#pragma unroll
            for (int j = 0; j < 4; j++) v[j] = acc[i][j][r] + bgv[j];
            float t1 = v[0], t2 = NINF;
            int c1 = nb * 128 + wcol + m16;
#pragma unroll
            for (int j = 1; j < 4; j++) {
                const int cj = nb * 128 + wcol + j * 16 + m16;
                if (v[j] > t1) { t2 = t1; t1 = v[j]; c1 = cj; }
                else t2 = fmaxf(t2, v[j]);
            }
#pragma unroll
            for (int mask = 1; mask <= 8; mask <<= 1) {
                float o1 = __shfl_xor(t1, mask, 64);
                int   oc = __shfl_xor(c1, mask, 64);
                float o2 = __shfl_xor(t2, mask, 64);
                if (o1 > t1 || (o1 == t1 && oc < c1)) {
                    t2 = fmaxf(t1, o2); t1 = o1; c1 = oc;
                } else {
                    t2 = fmaxf(t2, o1);
                }
            }
            float s = expf(v[0] - t1) + expf(v[1] - t1) +
                      expf(v[2] - t1) + expf(v[3] - t1);
#pragma unroll
            for (int mask = 1; mask <= 8; mask <<= 1)
                s += __shfl_xor(s, mask, 64);
            if (m16 == 0) {
                float4 st; st.x = t1; st.y = t2; st.z = s; st.w = __int_as_float(c1);
                stat[rloc][half] = st;
            }
        }
    }
    __syncthreads();
    if (tid < 128) {
        float4 h0 = stat[tid][0], h1 = stat[tid][1];
        float T1 = h0.x, T2 = h0.y, S;
        int C = __float_as_int(h0.w);
        if (h1.x > T1) {
            T2 = fmaxf(T1, h1.y);
            S = h0.z * expf(T1 - h1.x) + h1.z;
            T1 = h1.x; C = __float_as_int(h1.w);
        } else {
            T2 = fmaxf(T2, h1.x);
            S = h0.z + h1.z * expf(h1.x - T1);
        }
        float4 o; o.x = T1; o.y = T2; o.z = S; o.w = __int_as_float(C);
        partials[(size_t)nb * TOK + rb * 128 + tid] = o;
    }
}

// ---------------------------------------------------------------------------
// Combine partials -> p, expert; assign slots (block-aggregated atomics:
// 8 global atomics per block). Ambiguous rows deferred to fixup.
// ---------------------------------------------------------------------------
__global__ __launch_bounds__(256) void row_combine(
    const float4* __restrict__ partials, float* __restrict__ pout,
    int* __restrict__ cursor, int* __restrict__ row_of_slot,
    int* __restrict__ slot_of, int* __restrict__ ambig, int* __restrict__ n_ambig)
{
    const int row = blockIdx.x * 256 + threadIdx.x;
    const int tid = threadIdx.x;
    float4 t = partials[row];
    float T1 = t.x, T2 = t.y, S = t.z;
    int C = __float_as_int(t.w);
#pragma unroll
    for (int nb = 1; nb < NEXP; nb++) {
        float4 u = partials[(size_t)nb * TOK + row];
        if (u.x > T1) {
            T2 = fmaxf(T1, u.y);
            S = S * expf(T1 - u.x) + u.z;
            T1 = u.x; C = __float_as_int(u.w);
        } else {
            T2 = fmaxf(T2, u.x);
            S += u.z * expf(u.x - T1);
        }
    }
    pout[row] = 1.0f / S;
    const int e = C & (NEXP - 1);
    const bool amb = (T1 - T2 < MARGIN);

    __shared__ int h[NEXP], base[NEXP], lh[NEXP];
    if (tid < NEXP) { h[tid] = 0; lh[tid] = 0; }
    __syncthreads();
    if (!amb) atomicAdd(&h[e], 1);
    __syncthreads();
    if (tid < NEXP && h[tid] > 0) base[tid] = atomicAdd(&cursor[tid], h[tid]);
    __syncthreads();
    if (!amb) {
        int r = atomicAdd(&lh[e], 1);
        int slot = e * CAP + base[e] + r;
        row_of_slot[slot] = row;
        slot_of[row] = slot;
    } else {
        int k = atomicAdd(n_ambig, 1);
        if (k < AMBIG_CAP) ambig[k] = row;
    }
}

// ---------------------------------------------------------------------------
// Fix-up: ambiguous rows recomputed whole-row in fp64 (coalesced k-major
// Wg reads), exact argmax (numpy first-occurrence) + exact p + slot assign.
// ---------------------------------------------------------------------------
__global__ __launch_bounds__(256) void fixup(
    const float* __restrict__ x, const float* __restrict__ Wg,
    const float* __restrict__ bg, const int* __restrict__ ambig,
    const int* __restrict__ n_ambig, int* __restrict__ cursor,
    int* __restrict__ row_of_slot, int* __restrict__ slot_of,
    float* __restrict__ pout)
{
    int n = *n_ambig; if (n > AMBIG_CAP) n = AMBIG_CAP;
    const int tid = threadIdx.x;
    __shared__ float xs[DDIM];
    __shared__ double sv[256];
    __shared__ int    si[256];
    for (int ii = blockIdx.x; ii < n; ii += 64) {
        const int row = ambig[ii];
        for (int k = tid; k < DDIM; k += 256) xs[k] = x[(size_t)row * DDIM + k];
        __syncthreads();
        double a0 = 0, a1 = 0, a2 = 0, a3 = 0;
        for (int k = 0; k < DDIM; k++) {
            const double xv = (double)xs[k];
            const float* wr = Wg + (size_t)k * DDIM;
            a0 += xv * (double)wr[tid];
            a1 += xv * (double)wr[tid + 256];
            a2 += xv * (double)wr[tid + 512];
            a3 += xv * (double)wr[tid + 768];
        }
        a0 += (double)bg[tid];       a1 += (double)bg[tid + 256];
        a2 += (double)bg[tid + 512]; a3 += (double)bg[tid + 768];
        double m = a0; int mc = tid;
        if (a1 > m) { m = a1; mc = tid + 256; }
        if (a2 > m) { m = a2; mc = tid + 512; }
        if (a3 > m) { m = a3; mc = tid + 768; }
        sv[tid] = m; si[tid] = mc;
        __syncthreads();
        for (int off = 128; off > 0; off >>= 1) {
            if (tid < off) {
                double ov = sv[tid + off]; int oi = si[tid + off];
                if (ov > sv[tid] || (ov == sv[tid] && oi < si[tid])) {
                    sv[tid] = ov; si[tid] = oi;
                }
            }
            __syncthreads();
        }
        const double M = sv[0];
        const int best = si[0];
        __syncthreads();
        double s = exp(a0 - M) + exp(a1 - M) + exp(a2 - M) + exp(a3 - M);
        sv[tid] = s;
        __syncthreads();
        for (int off = 128; off > 0; off >>= 1) {
            if (tid < off) sv[tid] += sv[tid + off];
            __syncthreads();
        }
        if (tid == 0) {
            const int e = best & (NEXP - 1);
            pout[row] = (float)(1.0 / sv[0]);
            int slot = e * CAP + atomicAdd(&cursor[e], 1);
            row_of_slot[slot] = row;
            slot_of[row] = slot;
        }
        __syncthreads();
    }
}

// ---------------------------------------------------------------------------
// Gather xh rows into expert-sorted buffer (coalesced both sides)
// ---------------------------------------------------------------------------
__global__ __launch_bounds__(256) void gather_sorted(
    const unsigned short* __restrict__ xh, const int* __restrict__ slot_of,
    unsigned short* __restrict__ xs)
{
    const int t = blockIdx.x;
    const int slot = slot_of[t];
    const int c = threadIdx.x * 4;
    *(ushort4*)&xs[(size_t)slot * DDIM + c] = *(const ushort4*)&xh[(size_t)t * DDIM + c];
}

// ---------------------------------------------------------------------------
// Expert GEMM, pure m97 shape: coalesced global_load_lds for A (sorted xs)
// and B (WeT). bf16 MFMA 16x16x32, 128x128 tile, BK=32.
// Epilogue: relu(acc+be)*p scattered to token rows. e = rb / CAPB.
// ---------------------------------------------------------------------------
__global__ __launch_bounds__(256) void expert_gemm(
    const unsigned short* __restrict__ xs, const unsigned short* __restrict__ WeT,
    const float* __restrict__ be, const float* __restrict__ p,
    const int* __restrict__ row_of_slot, float* __restrict__ out)
{
    __shared__ unsigned short Asm[128 * 32];
    __shared__ unsigned short Bsm[128 * 32];
    __shared__ int rs[128];
    const int rb = blockIdx.x;
    const int nb = blockIdx.y;
    const int e  = rb / CAPB;
    const int tid  = threadIdx.x;

    if (tid < 128) rs[tid] = row_of_slot[rb * 128 + tid];
    __syncthreads();
    if (rs[0] < 0) return;          // wholly-empty capacity block

    const int lane = tid & 63;
    const int wave = tid >> 6;
    const int q    = lane >> 4;
    const int m16  = lane & 15;
    const int wrow = (wave & 1) * 64;
    const int wcol = (wave >> 1) * 64;
    const int xq   = (q ^ (m16 & 3)) * 8;

    const unsigned short* Aglob = xs + (size_t)rb * 128 * DDIM;
    const unsigned short* Bglob = WeT + (size_t)e * DDIM * DDIM + (size_t)nb * 128 * DDIM;

    f32x4 acc[4][4];
#pragma unroll
    for (int i = 0; i < 4; i++)
#pragma unroll
        for (int j = 0; j < 4; j++) acc[i][j] = (f32x4){0.f, 0.f, 0.f, 0.f};

    for (int k0 = 0; k0 < DDIM; k0 += 32) {
#pragma unroll
        for (int i = 0; i < 2; i++) {
            const int idx = tid + i * 256;
            const int r = idx >> 2;
            const int kk = ((idx & 3) ^ (r & 3)) * 8;
            const size_t go = (size_t)r * DDIM + k0 + kk;
            gload_lds16(Aglob + go, &Asm[idx * 8]);
            gload_lds16(Bglob + go, &Bsm[idx * 8]);
        }
        __syncthreads();
        bf16x8 af[4], bfr[4];
#pragma unroll
        for (int i = 0; i < 4; i++)
            af[i] = *(const bf16x8*)&Asm[(wrow + i * 16 + m16) * 32 + xq];
#pragma unroll
        for (int j = 0; j < 4; j++)
            bfr[j] = *(const bf16x8*)&Bsm[(wcol + j * 16 + m16) * 32 + xq];
#pragma unroll
        for (int i = 0; i < 4; i++)
#pragma unroll
            for (int j = 0; j < 4; j++)
                acc[i][j] = __builtin_amdgcn_mfma_f32_16x16x32_bf16(
                    af[i], bfr[j], acc[i][j], 0, 0, 0);
        __syncthreads();
    }

    float bev[4];
#pragma unroll
    for (int j = 0; j < 4; j++) bev[j] = be[e * DDIM + nb * 128 + wcol + j * 16 + m16];
#pragma unroll
    for (int i = 0; i < 4; i++)
#pragma unroll
        for (int r = 0; r < 4; r++) {
            const int t = rs[wrow + i * 16 + q * 4 + r];
            if (t < 0) continue;
            const float pv = p[t];
#pragma unroll
            for (int j = 0; j < 4; j++) {
                const int n = nb * 128 + wcol + j * 16 + m16;
                float v = acc[i][j][r] + bev[j];
                v = v > 0.f ? v : 0.f;
                out[(size_t)t * DDIM + n] = v * pv;
            }
        }
}

// ---------------------------------------------------------------------------
extern "C" void kernel_launch(void* const* d_in, const int* in_sizes, int n_in,
                              void* d_out, int out_size, void* d_ws, size_t ws_size,
                              hipStream_t stream)
{
    const float* x  = (const float*)d_in[0];
    const float* Wg = (const float*)d_in[1];
    const float* bg = (const float*)d_in[2];
    const float* We = (const float*)d_in[3];
    const float* be = (const float*)d_in[4];
    float* out = (float*)d_out;

    char* ws = (char*)d_ws;
    unsigned short* xh = (unsigned short*)ws;   ws += (size_t)TOK * DDIM * 2;
    unsigned short* WeT = (unsigned short*)ws;  ws += (size_t)NEXP * DDIM * DDIM * 2;
    unsigned short* WgTh = (unsigned short*)ws; ws += (size_t)DDIM * DDIM * 2;
    unsigned short* WgTl = (unsigned short*)ws; ws += (size_t)DDIM * DDIM * 2;
    float4* partials = (float4*)ws;             ws += (size_t)NEXP * TOK * 16;
    float* p = (float*)ws;                      ws += (size_t)TOK * 4;
    int* slot_of = (int*)ws;                    ws += (size_t)TOK * 4;
    int* row_of_slot = (int*)ws;                ws += (size_t)NRB * 128 * 4;
    int* cursor = (int*)ws;                     ws += NEXP * 4;
    int* n_ambig = (int*)ws;                    ws += 4;
    int* ambig = (int*)ws;                      ws += AMBIG_CAP * 4;
    unsigned short* xl = (unsigned short*)ws;   // 32 MB, dead after gating
    unsigned short* xs = (unsigned short*)ws;   // aliases xl + 9 MB beyond (gather runs after gating)

    hipMemsetAsync(cursor, 0, (NEXP + 1) * 4, stream);          // cursor + n_ambig
    hipMemsetAsync(row_of_slot, 0xFF, (size_t)NRB * 128 * 4, stream);

    prep_weights<<<dim3(32, 32, NEXP + 1), dim3(32, 8), 0, stream>>>(We, Wg, WeT, WgTh, WgTl);
    xsplit<<<TOK * DDIM / 1024, 256, 0, stream>>>(x, xh, xl);
    gating_mfma<<<dim3(TOK / 128, DDIM / 128), 256, 0, stream>>>(
        xh, xl, WgTh, WgTl, bg, partials);
    row_combine<<<TOK / 256, 256, 0, stream>>>(
        partials, p, cursor, row_of_slot, slot_of, ambig, n_ambig);
    fixup<<<64, 256, 0, stream>>>(x, Wg, bg, ambig, n_ambig, cursor,
                                  row_of_slot, slot_of, p);
    gather_sorted<<<TOK, 256, 0, stream>>>(xh, slot_of, xs);
    expert_gemm<<<dim3(NRB, DDIM / 128), 256, 0, stream>>>(
        xs, WeT, be, p, row_of_slot, out);
}